// Round 1
// baseline (1654.577 us; speedup 1.0000x reference)
//
#include <hip/hip_runtime.h>
#include <hip/hip_bf16.h>

// Problem constants (from reference): B=32768, S=1, I=128, H=256, L=2, A=32
#define NB 32768
#define ID 128
#define HD 256
#define AD 32
#define RT 16      // batch rows per block
#define NTH 256    // threads per block (thread j <-> hidden column j)

__device__ __forceinline__ float sig(float v) { return 1.0f / (1.0f + __expf(-v)); }

// One GRU layer for RT rows. Thread j (0..255) owns hidden column j.
// xs_ : LDS input activations, RT rows of stride KX (layer0: x, layer1: h0')
// hs_ : LDS hidden state, RT rows of stride HD; updated IN PLACE to h'.
// outh: global h_new[layer] base (B x HD, row-major)
template<int KX>
__device__ void gru_layer(const float* __restrict__ xs_, float* __restrict__ hs_,
                          const float* __restrict__ wih, const float* __restrict__ whh,
                          const float* __restrict__ bih, const float* __restrict__ bhh,
                          float* __restrict__ outh, int row0, int j)
{
    float ar[RT], az[RT], an[RT], hn[RT];
    const float bi_r = bih[j], bi_z = bih[j + HD], bi_n = bih[j + 2 * HD];
    const float bh_r = bhh[j], bh_z = bhh[j + HD], bh_n = bhh[j + 2 * HD];
#pragma unroll
    for (int r = 0; r < RT; ++r) {
        ar[r] = bi_r + bh_r;   // i_r + h_r accumulate together
        az[r] = bi_z + bh_z;   // i_z + h_z accumulate together
        an[r] = bi_n;          // i_n (kept separate: n = tanh(i_n + r*h_n))
        hn[r] = bh_n;          // h_n
    }

    // x-side: gi = x @ w_ih^T   (per-lane contiguous float4 weight reads along K)
    const float* wr_ = wih + (size_t)j * KX;
    const float* wz_ = wih + (size_t)(j + HD) * KX;
    const float* wn_ = wih + (size_t)(j + 2 * HD) * KX;
    for (int k = 0; k < KX; k += 4) {
        float4 wr = *reinterpret_cast<const float4*>(wr_ + k);
        float4 wz = *reinterpret_cast<const float4*>(wz_ + k);
        float4 wn = *reinterpret_cast<const float4*>(wn_ + k);
#pragma unroll
        for (int r = 0; r < RT; ++r) {
            float4 xv = *reinterpret_cast<const float4*>(xs_ + r * KX + k);  // uniform -> LDS broadcast
            ar[r] += wr.x * xv.x + wr.y * xv.y + wr.z * xv.z + wr.w * xv.w;
            az[r] += wz.x * xv.x + wz.y * xv.y + wz.z * xv.z + wz.w * xv.w;
            an[r] += wn.x * xv.x + wn.y * xv.y + wn.z * xv.z + wn.w * xv.w;
        }
    }

    // h-side: gh = h @ w_hh^T
    const float* vr_ = whh + (size_t)j * HD;
    const float* vz_ = whh + (size_t)(j + HD) * HD;
    const float* vn_ = whh + (size_t)(j + 2 * HD) * HD;
    for (int k = 0; k < HD; k += 4) {
        float4 wr = *reinterpret_cast<const float4*>(vr_ + k);
        float4 wz = *reinterpret_cast<const float4*>(vz_ + k);
        float4 wn = *reinterpret_cast<const float4*>(vn_ + k);
#pragma unroll
        for (int r = 0; r < RT; ++r) {
            float4 hv = *reinterpret_cast<const float4*>(hs_ + r * HD + k);  // uniform -> LDS broadcast
            ar[r] += wr.x * hv.x + wr.y * hv.y + wr.z * hv.z + wr.w * hv.w;
            az[r] += wz.x * hv.x + wz.y * hv.y + wz.z * hv.z + wz.w * hv.w;
            hn[r] += wn.x * hv.x + wn.y * hv.y + wn.z * hv.z + wn.w * hv.w;
        }
    }

    __syncthreads();  // everyone done READING hs_ before in-place update

#pragma unroll
    for (int r = 0; r < RT; ++r) {
        float rg = sig(ar[r]);
        float zg = sig(az[r]);
        float n  = tanhf(an[r] + rg * hn[r]);
        float hp = hs_[r * HD + j];                 // own column only
        float hnew = (1.0f - zg) * n + zg * hp;
        hs_[r * HD + j] = hnew;                     // own column only
        outh[(size_t)(row0 + r) * HD + j] = hnew;   // coalesced across j
    }
}

__global__ __launch_bounds__(NTH) void gru_fused(
    const float* __restrict__ x, const float* __restrict__ h,
    const float* __restrict__ wih0, const float* __restrict__ whh0,
    const float* __restrict__ bih0, const float* __restrict__ bhh0,
    const float* __restrict__ wih1, const float* __restrict__ whh1,
    const float* __restrict__ bih1, const float* __restrict__ bhh1,
    const float* __restrict__ wp, const float* __restrict__ bp,
    const float* __restrict__ wv, const float* __restrict__ bv,
    float* __restrict__ out)
{
    __shared__ float xs[RT][ID];    // 8 KB
    __shared__ float h0s[RT][HD];   // 16 KB : h0, then h0' in place
    __shared__ float h1s[RT][HD];   // 16 KB : h1, then h1' in place

    const int t = threadIdx.x;
    const int row0 = blockIdx.x * RT;

    float* out_logits = out;                               // (B, 32)
    float* out_value  = out + (size_t)NB * AD;             // (B,)
    float* out_h      = out_value + NB;                    // (2, B, HD)

    // ---- stage x (16x128), h0 (16x256), h1 (16x256) as float4, coalesced ----
    {
        const float4* xg = reinterpret_cast<const float4*>(x + (size_t)row0 * ID);
        float4* xl = reinterpret_cast<float4*>(&xs[0][0]);
        xl[t]       = xg[t];
        xl[t + NTH] = xg[t + NTH];
        const float4* g0 = reinterpret_cast<const float4*>(h + (size_t)row0 * HD);
        const float4* g1 = reinterpret_cast<const float4*>(h + (size_t)NB * HD + (size_t)row0 * HD);
        float4* l0 = reinterpret_cast<float4*>(&h0s[0][0]);
        float4* l1 = reinterpret_cast<float4*>(&h1s[0][0]);
#pragma unroll
        for (int i = 0; i < 4; ++i) {
            l0[t + i * NTH] = g0[t + i * NTH];
            l1[t + i * NTH] = g1[t + i * NTH];
        }
    }
    __syncthreads();

    // layer 0: inputs xs (K=128), state h0s -> h0' (in place + global)
    gru_layer<ID>(&xs[0][0], &h0s[0][0], wih0, whh0, bih0, bhh0, out_h, row0, t);
    __syncthreads();

    // layer 1: inputs h0' (K=256), state h1s -> h1'
    gru_layer<HD>(&h0s[0][0], &h1s[0][0], wih1, whh1, bih1, bhh1,
                  out_h + (size_t)NB * HD, row0, t);
    __syncthreads();

    // ---- heads ----
    // logits: thread t -> (a = t&31, row group t>>5); 2 iterations cover 16 rows
    {
        const int a = t & 31;
        const int rg0 = t >> 5;
#pragma unroll
        for (int rr = 0; rr < RT; rr += 8) {
            const int r = rg0 + rr;
            float acc = bp[a];
            const float* wa = wp + (size_t)a * HD;
            for (int k = 0; k < HD; k += 4) {
                float4 w4 = *reinterpret_cast<const float4*>(wa + k);
                float4 h4 = *reinterpret_cast<const float4*>(&h1s[r][k]);
                acc += w4.x * h4.x + w4.y * h4.y + w4.z * h4.z + w4.w * h4.w;
            }
            out_logits[(size_t)(row0 + r) * AD + a] = acc;
        }
    }
    // value: one thread per row (tiny tail)
    if (t < RT) {
        float acc = bv[0];
        for (int k = 0; k < HD; k += 4) {
            float4 w4 = *reinterpret_cast<const float4*>(wv + k);
            float4 h4 = *reinterpret_cast<const float4*>(&h1s[t][k]);
            acc += w4.x * h4.x + w4.y * h4.y + w4.z * h4.z + w4.w * h4.w;
        }
        out_value[row0 + t] = acc;
    }
}

extern "C" void kernel_launch(void* const* d_in, const int* in_sizes, int n_in,
                              void* d_out, int out_size, void* d_ws, size_t ws_size,
                              hipStream_t stream) {
    const float* x    = (const float*)d_in[0];
    const float* h    = (const float*)d_in[1];
    const float* wih0 = (const float*)d_in[2];
    const float* whh0 = (const float*)d_in[3];
    const float* bih0 = (const float*)d_in[4];
    const float* bhh0 = (const float*)d_in[5];
    const float* wih1 = (const float*)d_in[6];
    const float* whh1 = (const float*)d_in[7];
    const float* bih1 = (const float*)d_in[8];
    const float* bhh1 = (const float*)d_in[9];
    const float* wp   = (const float*)d_in[10];
    const float* bp   = (const float*)d_in[11];
    const float* wv   = (const float*)d_in[12];
    const float* bv   = (const float*)d_in[13];

    gru_fused<<<NB / RT, NTH, 0, stream>>>(x, h, wih0, whh0, bih0, bhh0,
                                           wih1, whh1, bih1, bhh1,
                                           wp, bp, wv, bv, (float*)d_out);
}

// Round 2
// 495.451 us; speedup vs baseline: 3.3395x; 3.3395x over previous
//
#include <hip/hip_runtime.h>
#include <hip/hip_bf16.h>
#include <stdint.h>

// B=32768, S=1, I=128, H=256, L=2, A=32
#define NB 32768
#define ID 128
#define HD 256
#define AD 32
#define BM 64          // batch rows per block
#define NTH 256        // 4 waves
#define NBLK (NB / BM) // 512 blocks

typedef unsigned int u32;
typedef unsigned short u16;
typedef __attribute__((ext_vector_type(8))) short bf16x8;  // 8 bf16 = 4 VGPR
typedef __attribute__((ext_vector_type(4))) float f32x4;
typedef __attribute__((ext_vector_type(2))) u32 u32x2;

// bf16 weight workspace layout (elements)
#define OFF_W0X 0               // 768x128
#define OFF_W0H 98304           // 768x256
#define OFF_W1X 294912          // 768x256
#define OFF_W1H 491520          // 768x256
#define OFF_WHD 688128          // 48x256 (wp rows 0-31, wv row 32, 0 pad)
#define W_TOTAL 700416

__device__ __forceinline__ u16 f2bf(float f) {  // round-to-nearest-even
    u32 u = __builtin_bit_cast(u32, f);
    return (u16)((u + 0x7FFFu + ((u >> 16) & 1u)) >> 16);
}
__device__ __forceinline__ float sigf(float v) { return 1.0f / (1.0f + __expf(-v)); }
__device__ __forceinline__ float tanh_fast(float v) { return 1.0f - 2.0f / (1.0f + __expf(2.0f * v)); }

__global__ void prep_weights(const float* __restrict__ wih0, const float* __restrict__ whh0,
                             const float* __restrict__ wih1, const float* __restrict__ whh1,
                             const float* __restrict__ wp, const float* __restrict__ wv,
                             u16* __restrict__ wb) {
    int i = blockIdx.x * blockDim.x + threadIdx.x;
    if (i >= W_TOTAL) return;
    float v;
    if (i < OFF_W0H)      v = wih0[i];
    else if (i < OFF_W1X) v = whh0[i - OFF_W0H];
    else if (i < OFF_W1H) v = wih1[i - OFF_W1X];
    else if (i < OFF_WHD) v = whh1[i - OFF_W1H];
    else {
        int j = i - OFF_WHD;
        int r = j >> 8, k = j & 255;
        v = (r < AD) ? wp[j] : ((r == AD) ? wv[k] : 0.0f);
    }
    wb[i] = f2bf(v);
}

// swizzled LDS byte address: row-major tile, rowstride bytes, XOR (row&7)<<4
#define SWZ(row, kbyte, rowstride) ((((row) * (rowstride)) + (kbyte)) ^ (((row) & 7) << 4))

#define MFMA(a, b, c) __builtin_amdgcn_mfma_f32_16x16x32_bf16((a), (b), (c), 0, 0, 0)

// One GRU layer gate GEMM for the wave's 16 cols x 64 rows, chunk col base given by `col`.
// Ax: LDS A-tile for x-side (K=KA, stride KA*2 bytes, swizzled)
// Ah: LDS A-tile for h-side (K=256, stride 512, swizzled)
// Wx/Wh: bf16 weights, rows = gate cols ([r|z|n] blocks of HD), row-major K
template<int KA>
__device__ __forceinline__ void gate_gemm(
    const char* __restrict__ Ax, const char* __restrict__ Ah,
    const u16* __restrict__ Wx, const u16* __restrict__ Wh,
    int col, int lane,
    f32x4 accr[4], f32x4 accz[4], f32x4 accni[4], f32x4 accnh[4])
{
    const int krow = (lane >> 4) * 8;   // k-offset of this lane group
    const int arow = lane & 15;
#pragma unroll
    for (int ks = 0; ks < KA / 32; ++ks) {          // x-side: r, z, i_n
        const int kb = ks * 32 + krow;
        bf16x8 wr = *(const bf16x8*)(Wx + (size_t)col * KA + kb);
        bf16x8 wz = *(const bf16x8*)(Wx + (size_t)(HD + col) * KA + kb);
        bf16x8 wn = *(const bf16x8*)(Wx + (size_t)(2 * HD + col) * KA + kb);
#pragma unroll
        for (int m = 0; m < 4; ++m) {
            const int row = m * 16 + arow;
            bf16x8 a = *(const bf16x8*)(Ax + SWZ(row, kb * 2, KA * 2));
            accr[m]  = MFMA(a, wr, accr[m]);
            accz[m]  = MFMA(a, wz, accz[m]);
            accni[m] = MFMA(a, wn, accni[m]);
        }
    }
#pragma unroll
    for (int ks = 0; ks < 8; ++ks) {                // h-side: r, z, h_n
        const int kb = ks * 32 + krow;
        bf16x8 wr = *(const bf16x8*)(Wh + (size_t)col * HD + kb);
        bf16x8 wz = *(const bf16x8*)(Wh + (size_t)(HD + col) * HD + kb);
        bf16x8 wn = *(const bf16x8*)(Wh + (size_t)(2 * HD + col) * HD + kb);
#pragma unroll
        for (int m = 0; m < 4; ++m) {
            const int row = m * 16 + arow;
            bf16x8 a = *(const bf16x8*)(Ah + SWZ(row, kb * 2, 512));
            accr[m]  = MFMA(a, wr, accr[m]);
            accz[m]  = MFMA(a, wz, accz[m]);
            accnh[m] = MFMA(a, wn, accnh[m]);
        }
    }
}

// Full layer: 4 col-chunks of 64 (wave takes 16 cols each). h' -> global fp32 + bf16 reg stash.
template<int KA>
__device__ __forceinline__ void gru_layer_mfma(
    const char* __restrict__ Ax, const char* __restrict__ Ah,
    const u16* __restrict__ Wx, const u16* __restrict__ Wh,
    const float* __restrict__ bi, const float* __restrict__ bh,
    const float* __restrict__ hprev_g, float* __restrict__ hout_g,
    int row0, int lane, int w, u32 st[4][4][2])
{
#pragma unroll
    for (int c = 0; c < 4; ++c) {
        const int col = c * 64 + (w << 4) + (lane & 15);
        const float br  = bi[col] + bh[col];
        const float bz  = bi[HD + col] + bh[HD + col];
        const float bni = bi[2 * HD + col];
        const float bnh = bh[2 * HD + col];
        f32x4 accr[4], accz[4], accni[4], accnh[4];
#pragma unroll
        for (int m = 0; m < 4; ++m) {
            accr[m]  = f32x4{br, br, br, br};
            accz[m]  = f32x4{bz, bz, bz, bz};
            accni[m] = f32x4{bni, bni, bni, bni};
            accnh[m] = f32x4{bnh, bnh, bnh, bnh};
        }
        gate_gemm<KA>(Ax, Ah, Wx, Wh, col, lane, accr, accz, accni, accnh);
#pragma unroll
        for (int m = 0; m < 4; ++m) {
            const int rowg = m * 16 + ((lane >> 4) << 2);   // C layout: row=(l>>4)*4+reg
#pragma unroll
            for (int pq = 0; pq < 2; ++pq) {
                u32 pk = 0;
#pragma unroll
                for (int q2 = 0; q2 < 2; ++q2) {
                    const int q = pq * 2 + q2;
                    float rg = sigf(accr[m][q]);
                    float zg = sigf(accz[m][q]);
                    float n  = tanh_fast(accni[m][q] + rg * accnh[m][q]);
                    float hp = hprev_g[(size_t)(row0 + rowg + q) * HD + col];
                    float hv = (1.0f - zg) * n + zg * hp;
                    hout_g[(size_t)(row0 + rowg + q) * HD + col] = hv;
                    pk |= (u32)f2bf(hv) << (16 * q2);
                }
                st[c][m][pq] = pk;
            }
        }
    }
}

__device__ __forceinline__ void write_stash(char* __restrict__ R, u32 st[4][4][2],
                                            int lane, int w) {
#pragma unroll
    for (int c = 0; c < 4; ++c)
#pragma unroll
        for (int m = 0; m < 4; ++m) {
            const int colb = (c * 64 + (w << 4) + (lane & 15)) * 2;
            const int rowg = m * 16 + ((lane >> 4) << 2);
            *(u16*)(R + SWZ(rowg + 0, colb, 512)) = (u16)(st[c][m][0]);
            *(u16*)(R + SWZ(rowg + 1, colb, 512)) = (u16)(st[c][m][0] >> 16);
            *(u16*)(R + SWZ(rowg + 2, colb, 512)) = (u16)(st[c][m][1]);
            *(u16*)(R + SWZ(rowg + 3, colb, 512)) = (u16)(st[c][m][1] >> 16);
        }
}

__global__ __launch_bounds__(NTH, 2) void gru_mfma(
    const float* __restrict__ x, const float* __restrict__ h,
    const float* __restrict__ bih0, const float* __restrict__ bhh0,
    const float* __restrict__ bih1, const float* __restrict__ bhh1,
    const float* __restrict__ bp, const float* __restrict__ bv,
    const u16* __restrict__ wb, float* __restrict__ out)
{
    __shared__ uint4 lds4[81920 / 16];           // 80 KB -> 2 blocks/CU
    char* lds = (char*)lds4;
    char* R1 = lds;             // x tile: 64 x 128 bf16, stride 256B (swz)
    char* R2 = lds + 16384;     // h0 -> h0' -> h1' : 64 x 256 bf16, stride 512B (swz)
    char* R3 = lds + 49152;     // h1

    const int t = threadIdx.x;
    const int lane = t & 63;
    const int w = t >> 6;
    const int row0 = blockIdx.x * BM;

    const u16* W0x = wb + OFF_W0X;
    const u16* W0h = wb + OFF_W0H;
    const u16* W1x = wb + OFF_W1X;
    const u16* W1h = wb + OFF_W1H;
    const u16* Whd = wb + OFF_WHD;

    float* out_logits = out;
    float* out_value  = out + (size_t)NB * AD;
    float* out_h0     = out_value + NB;
    float* out_h1     = out_h0 + (size_t)NB * HD;

    // ---- stage x, h0, h1 (fp32 -> bf16, swizzled, coalesced float4 reads) ----
    {
        const float4* xg = (const float4*)(x + (size_t)row0 * ID);
#pragma unroll
        for (int it = 0; it < 8; ++it) {
            int i = t + it * NTH;                 // 2048 float4
            float4 v = xg[i];
            int rowi = i >> 5;                    // 32 float4/row
            int kb = (i & 31) * 8;                // bf16 byte offset
            u32x2 b;
            b[0] = (u32)f2bf(v.x) | ((u32)f2bf(v.y) << 16);
            b[1] = (u32)f2bf(v.z) | ((u32)f2bf(v.w) << 16);
            *(u32x2*)(R1 + SWZ(rowi, kb, 256)) = b;
        }
        const float4* h0g = (const float4*)(h + (size_t)row0 * HD);
        const float4* h1g = (const float4*)(h + (size_t)NB * HD + (size_t)row0 * HD);
#pragma unroll
        for (int it = 0; it < 16; ++it) {
            int i = t + it * NTH;                 // 4096 float4
            int rowi = i >> 6;                    // 64 float4/row
            int kb = (i & 63) * 8;
            float4 v0 = h0g[i];
            u32x2 b0;
            b0[0] = (u32)f2bf(v0.x) | ((u32)f2bf(v0.y) << 16);
            b0[1] = (u32)f2bf(v0.z) | ((u32)f2bf(v0.w) << 16);
            *(u32x2*)(R2 + SWZ(rowi, kb, 512)) = b0;
            float4 v1 = h1g[i];
            u32x2 b1;
            b1[0] = (u32)f2bf(v1.x) | ((u32)f2bf(v1.y) << 16);
            b1[1] = (u32)f2bf(v1.z) | ((u32)f2bf(v1.w) << 16);
            *(u32x2*)(R3 + SWZ(rowi, kb, 512)) = b1;
        }
    }
    __syncthreads();

    u32 st[4][4][2];
    // ---- layer 0: A_x = x (R1), A_h = h0 (R2) ----
    gru_layer_mfma<ID>(R1, R2, W0x, W0h, bih0, bhh0, h, out_h0, row0, lane, w, st);
    __syncthreads();                 // all waves done reading h0
    write_stash(R2, st, lane, w);    // R2 := h0' (bf16)
    __syncthreads();

    // ---- layer 1: A_x = h0' (R2), A_h = h1 (R3) ----
    gru_layer_mfma<HD>(R2, R3, W1x, W1h, bih1, bhh1,
                       h + (size_t)NB * HD, out_h1, row0, lane, w, st);
    __syncthreads();                 // all waves done reading h0'/h1
    write_stash(R2, st, lane, w);    // R2 := h1' (bf16)
    __syncthreads();

    // ---- heads: [logits(32) | value(1) | pad] = h1' @ Whd^T, N=48, K=256 ----
    {
        const int m = w;                          // wave w -> rows m*16..+15
        const int arow = lane & 15;
        const int krow = (lane >> 4) * 8;
        float b0 = bp[arow], b1 = bp[16 + arow], b2 = bv[0];
        f32x4 acc[3];
        acc[0] = f32x4{b0, b0, b0, b0};
        acc[1] = f32x4{b1, b1, b1, b1};
        acc[2] = f32x4{b2, b2, b2, b2};
#pragma unroll
        for (int ks = 0; ks < 8; ++ks) {
            const int kb = ks * 32 + krow;
            const int row = m * 16 + arow;
            bf16x8 a = *(const bf16x8*)(R2 + SWZ(row, kb * 2, 512));
#pragma unroll
            for (int f = 0; f < 3; ++f) {
                bf16x8 wf = *(const bf16x8*)(Whd + (size_t)(f * 16 + arow) * HD + kb);
                acc[f] = MFMA(a, wf, acc[f]);
            }
        }
        const int rowg = m * 16 + ((lane >> 4) << 2);
#pragma unroll
        for (int q = 0; q < 4; ++q) {
            out_logits[(size_t)(row0 + rowg + q) * AD + arow]      = acc[0][q];
            out_logits[(size_t)(row0 + rowg + q) * AD + 16 + arow] = acc[1][q];
        }
        if (arow == 0) {
#pragma unroll
            for (int q = 0; q < 4; ++q)
                out_value[row0 + rowg + q] = acc[2][q];
        }
    }
}

extern "C" void kernel_launch(void* const* d_in, const int* in_sizes, int n_in,
                              void* d_out, int out_size, void* d_ws, size_t ws_size,
                              hipStream_t stream) {
    const float* x    = (const float*)d_in[0];
    const float* h    = (const float*)d_in[1];
    const float* wih0 = (const float*)d_in[2];
    const float* whh0 = (const float*)d_in[3];
    const float* bih0 = (const float*)d_in[4];
    const float* bhh0 = (const float*)d_in[5];
    const float* wih1 = (const float*)d_in[6];
    const float* whh1 = (const float*)d_in[7];
    const float* bih1 = (const float*)d_in[8];
    const float* bhh1 = (const float*)d_in[9];
    const float* wp   = (const float*)d_in[10];
    const float* bp   = (const float*)d_in[11];
    const float* wv   = (const float*)d_in[12];
    const float* bv   = (const float*)d_in[13];

    u16* wb = (u16*)d_ws;   // 1.37 MB bf16 weights
    prep_weights<<<(W_TOTAL + 255) / 256, 256, 0, stream>>>(wih0, whh0, wih1, whh1, wp, wv, wb);
    gru_mfma<<<NBLK, NTH, 0, stream>>>(x, h, bih0, bhh0, bih1, bhh1, bp, bv, wb, (float*)d_out);
}